// Round 1
// baseline (5862.965 us; speedup 1.0000x reference)
//
#include <hip/hip_runtime.h>

// VQ-VAE EMA vector quantizer, MI355X baseline (f32 vector path)
// z_e [32,1024,512] f32, codebook [8192,512] f32, cluster_size [8192], ema_w [8192,512]

constexpr int N = 32768;   // B*L
constexpr int D = 512;
constexpr int K = 8192;

constexpr float DECAYF  = 0.99f;
constexpr float OMDECAY = (float)(1.0 - 0.99);       // matches jnp f32 cast of python (1.0-DECAY)
constexpr float EPSF    = 1e-6f;
constexpr float KEPSF   = (float)(8192 * 1e-6);      // K * EPS in f64 then cast

// ---- workspace layout (float offsets) ----
constexpr size_t OFF_CNORM  = 0;                      // K
constexpr size_t OFF_XNORM  = OFF_CNORM + K;          // N
constexpr size_t OFF_IDX    = OFF_XNORM + N;          // N (int32)
constexpr size_t OFF_COUNTS = OFF_IDX + N;            // K
constexpr size_t OFF_DW     = OFF_COUNTS + K;         // K*D
constexpr size_t OFF_SUMS   = OFF_DW + (size_t)K * D; // 4 floats = 2 doubles (loss_sum, n_sum)
constexpr size_t WS_FLOATS  = OFF_SUMS + 4;

// ---- output layout (float offsets), reference return order ----
constexpr size_t OUT_ZQ   = 0;                          // N*D
constexpr size_t OUT_IDX  = OUT_ZQ + (size_t)N * D;     // N
constexpr size_t OUT_LOSS = OUT_IDX + N;                // 1
constexpr size_t OUT_NCB  = OUT_LOSS + 1;               // K*D
constexpr size_t OUT_NCS  = OUT_NCB + (size_t)K * D;    // K
constexpr size_t OUT_EMA  = OUT_NCS + K;                // K*D

// ---------------------------------------------------------------------------
__global__ __launch_bounds__(256) void row_norm_kernel(const float* __restrict__ a,
                                                       float* __restrict__ out)
{
    const int row  = blockIdx.x * 4 + (threadIdx.x >> 6);
    const int lane = threadIdx.x & 63;
    const float4* r = (const float4*)(a + (size_t)row * D);
    const float4 v0 = r[lane];
    const float4 v1 = r[lane + 64];
    float s = v0.x * v0.x + v0.y * v0.y + v0.z * v0.z + v0.w * v0.w
            + v1.x * v1.x + v1.y * v1.y + v1.z * v1.z + v1.w * v1.w;
#pragma unroll
    for (int m = 32; m >= 1; m >>= 1) s += __shfl_xor(s, m, 64);
    if (lane == 0) out[row] = s;
}

// ---------------------------------------------------------------------------
// Fused distance + argmin. Block: 64 points x (all K via 64-code tiles).
// 256 threads = 16x16, each thread owns a 4x4 (point x code) micro-tile.
__global__ __launch_bounds__(256) void argmin_kernel(
    const float* __restrict__ x, const float* __restrict__ cb,
    const float* __restrict__ xnorm, const float* __restrict__ cnorm,
    int* __restrict__ idx_i, float* __restrict__ idx_f)
{
    __shared__ float xs[32][64];   // [d][point]
    __shared__ float cs[32][64];   // [d][code]

    const int tid = threadIdx.x;
    const int tx  = tid & 15;      // code group
    const int ty  = tid >> 4;      // point group
    const int n0  = blockIdx.x * 64;

    const int lr = tid >> 3;         // load row 0..31
    const int lc = (tid & 7) << 2;   // load col (floats) 0,4,...,28

    float xn[4];
#pragma unroll
    for (int i = 0; i < 4; ++i) xn[i] = xnorm[n0 + ty * 4 + i];

    float best[4]  = {INFINITY, INFINITY, INFINITY, INFINITY};
    int   besti[4] = {0, 0, 0, 0};

    const float* xbase = x + (size_t)n0 * D;

    for (int k0 = 0; k0 < K; k0 += 64) {
        float acc[4][4];
#pragma unroll
        for (int i = 0; i < 4; ++i)
#pragma unroll
            for (int j = 0; j < 4; ++j) acc[i][j] = 0.0f;

        const float* cbase = cb + (size_t)k0 * D;

        for (int d0 = 0; d0 < D; d0 += 32) {
            __syncthreads();
            {
                float4 v;
                v = *(const float4*)(xbase + (size_t)lr * D + d0 + lc);
                xs[lc + 0][lr] = v.x; xs[lc + 1][lr] = v.y; xs[lc + 2][lr] = v.z; xs[lc + 3][lr] = v.w;
                v = *(const float4*)(xbase + (size_t)(lr + 32) * D + d0 + lc);
                xs[lc + 0][lr + 32] = v.x; xs[lc + 1][lr + 32] = v.y; xs[lc + 2][lr + 32] = v.z; xs[lc + 3][lr + 32] = v.w;
                v = *(const float4*)(cbase + (size_t)lr * D + d0 + lc);
                cs[lc + 0][lr] = v.x; cs[lc + 1][lr] = v.y; cs[lc + 2][lr] = v.z; cs[lc + 3][lr] = v.w;
                v = *(const float4*)(cbase + (size_t)(lr + 32) * D + d0 + lc);
                cs[lc + 0][lr + 32] = v.x; cs[lc + 1][lr + 32] = v.y; cs[lc + 2][lr + 32] = v.z; cs[lc + 3][lr + 32] = v.w;
            }
            __syncthreads();
#pragma unroll
            for (int dd = 0; dd < 32; ++dd) {
                const float4 xv = *(const float4*)&xs[dd][ty * 4];
                const float4 cv = *(const float4*)&cs[dd][tx * 4];
                const float xa[4] = {xv.x, xv.y, xv.z, xv.w};
                const float ca[4] = {cv.x, cv.y, cv.z, cv.w};
#pragma unroll
                for (int i = 0; i < 4; ++i)
#pragma unroll
                    for (int j = 0; j < 4; ++j)
                        acc[i][j] = fmaf(xa[i], ca[j], acc[i][j]);
            }
        }

        float cn[4];
#pragma unroll
        for (int j = 0; j < 4; ++j) cn[j] = cnorm[k0 + tx * 4 + j];

#pragma unroll
        for (int i = 0; i < 4; ++i) {
            float bv = INFINITY; int bi = 0x7fffffff;
#pragma unroll
            for (int j = 0; j < 4; ++j) {
                // same association as the reference: (||x||^2 - 2*dot) + ||c||^2
                const float dist = (xn[i] - 2.0f * acc[i][j]) + cn[j];
                const int kk = k0 + tx * 4 + j;
                if (dist < bv || (dist == bv && kk < bi)) { bv = dist; bi = kk; }
            }
            // butterfly reduce over the 16 tx lanes (same ty -> low 4 lane bits)
#pragma unroll
            for (int m = 1; m < 16; m <<= 1) {
                const float ov = __shfl_xor(bv, m, 64);
                const int   oi = __shfl_xor(bi, m, 64);
                if (ov < bv || (ov == bv && oi < bi)) { bv = ov; bi = oi; }
            }
            // k0 ascending + strict < keeps first occurrence (jnp.argmin semantics)
            if (bv < best[i]) { best[i] = bv; besti[i] = bi; }
        }
    }

    if (tx == 0) {
#pragma unroll
        for (int i = 0; i < 4; ++i) {
            const int n = n0 + ty * 4 + i;
            idx_i[n] = besti[i];
            idx_f[n] = (float)besti[i];
        }
    }
}

// ---------------------------------------------------------------------------
// Per-point: gather z_q, loss partial, scatter counts/dw.
__global__ __launch_bounds__(256) void scatter_kernel(
    const float* __restrict__ x, const float* __restrict__ cb,
    const int* __restrict__ idx_i, float* __restrict__ zq,
    float* __restrict__ counts, float* __restrict__ dw,
    double* __restrict__ loss_sum)
{
    const int n = blockIdx.x;
    const int k = idx_i[n];
    const int t = threadIdx.x;
    const size_t xoff = (size_t)n * D + t * 2;
    const size_t coff = (size_t)k * D + t * 2;

    const float2 xv = *(const float2*)(x + xoff);
    const float2 qv = *(const float2*)(cb + coff);
    *(float2*)(zq + xoff) = qv;

    const float dx = xv.x - qv.x, dy = xv.y - qv.y;
    float sq = dx * dx + dy * dy;

    atomicAdd(&dw[coff], xv.x);
    atomicAdd(&dw[coff + 1], xv.y);

#pragma unroll
    for (int m = 32; m >= 1; m >>= 1) sq += __shfl_xor(sq, m, 64);
    __shared__ float partial[4];
    if ((t & 63) == 0) partial[t >> 6] = sq;
    __syncthreads();
    if (t == 0) {
        atomicAdd(loss_sum, (double)(partial[0] + partial[1] + partial[2] + partial[3]));
        atomicAdd(&counts[k], 1.0f);
    }
}

// ---------------------------------------------------------------------------
__global__ __launch_bounds__(256) void csize_kernel(
    const float* __restrict__ csz, const float* __restrict__ counts,
    float* __restrict__ ncs, double* __restrict__ n_sum)
{
    const int k = blockIdx.x * 256 + threadIdx.x;
    const float v = DECAYF * csz[k] + OMDECAY * counts[k];
    ncs[k] = v;
    float s = v;
#pragma unroll
    for (int m = 32; m >= 1; m >>= 1) s += __shfl_xor(s, m, 64);
    __shared__ float partial[4];
    if ((threadIdx.x & 63) == 0) partial[threadIdx.x >> 6] = s;
    __syncthreads();
    if (threadIdx.x == 0)
        atomicAdd(n_sum, (double)(partial[0] + partial[1] + partial[2] + partial[3]));
}

// ---------------------------------------------------------------------------
__global__ __launch_bounds__(256) void finalize_kernel(
    const float* __restrict__ ema_w, const float* __restrict__ dw,
    const float* __restrict__ ncs, const double* __restrict__ n_sum,
    float* __restrict__ new_ema, float* __restrict__ new_cb)
{
    const int k = blockIdx.x;
    const float n = (float)n_sum[0];
    const float csm = (ncs[k] + EPSF) / (n + KEPSF) * n;
    const size_t base = (size_t)k * D + threadIdx.x * 2;

    const float2 e = *(const float2*)(ema_w + base);
    const float2 w = *(const float2*)(dw + base);
    float2 ne;
    ne.x = DECAYF * e.x + OMDECAY * w.x;
    ne.y = DECAYF * e.y + OMDECAY * w.y;
    *(float2*)(new_ema + base) = ne;
    float2 nc;
    nc.x = ne.x / csm;
    nc.y = ne.y / csm;
    *(float2*)(new_cb + base) = nc;
}

// ---------------------------------------------------------------------------
__global__ void loss_kernel(const double* __restrict__ loss_sum, float* __restrict__ out_loss)
{
    out_loss[0] = (float)(1.25 * (loss_sum[0] / (double)((size_t)N * D)));
}

// ---------------------------------------------------------------------------
extern "C" void kernel_launch(void* const* d_in, const int* in_sizes, int n_in,
                              void* d_out, int out_size, void* d_ws, size_t ws_size,
                              hipStream_t stream)
{
    const float* z_e   = (const float*)d_in[0];
    const float* cbook = (const float*)d_in[1];
    const float* csz   = (const float*)d_in[2];
    const float* ema_w = (const float*)d_in[3];

    float* out = (float*)d_out;
    float* ws  = (float*)d_ws;

    float*  cnorm    = ws + OFF_CNORM;
    float*  xnorm    = ws + OFF_XNORM;
    int*    idx_i    = (int*)(ws + OFF_IDX);
    float*  counts   = ws + OFF_COUNTS;
    float*  dw       = ws + OFF_DW;
    double* loss_sum = (double*)(ws + OFF_SUMS);
    double* n_sum    = loss_sum + 1;

    // zero the accumulators (counts, dw, sums) every launch
    hipMemsetAsync(counts, 0, (WS_FLOATS - OFF_COUNTS) * sizeof(float), stream);

    row_norm_kernel<<<K / 4, 256, 0, stream>>>(cbook, cnorm);
    row_norm_kernel<<<N / 4, 256, 0, stream>>>(z_e, xnorm);

    argmin_kernel<<<N / 64, 256, 0, stream>>>(z_e, cbook, xnorm, cnorm,
                                              idx_i, out + OUT_IDX);

    scatter_kernel<<<N, 256, 0, stream>>>(z_e, cbook, idx_i, out + OUT_ZQ,
                                          counts, dw, loss_sum);

    csize_kernel<<<K / 256, 256, 0, stream>>>(csz, counts, out + OUT_NCS, n_sum);

    finalize_kernel<<<K, 256, 0, stream>>>(ema_w, dw, out + OUT_NCS, n_sum,
                                           out + OUT_EMA, out + OUT_NCB);

    loss_kernel<<<1, 1, 0, stream>>>(loss_sum, out + OUT_LOSS);
}

// Round 2
// 1870.675 us; speedup vs baseline: 3.1341x; 3.1341x over previous
//
#include <hip/hip_runtime.h>

// VQ-VAE EMA vector quantizer, MI355X — MFMA bf16-split path
// z_e [32,1024,512] f32, codebook [8192,512] f32, cluster_size [8192], ema_w [8192,512]

constexpr int N = 32768;   // B*L
constexpr int D = 512;
constexpr int K = 8192;

constexpr float DECAYF  = 0.99f;
constexpr float OMDECAY = (float)(1.0 - 0.99);
constexpr float EPSF    = 1e-6f;
constexpr float KEPSF   = (float)(8192 * 1e-6);
constexpr float TAU     = 0.02f;   // gap threshold for exact re-check

typedef unsigned int   u32;
typedef unsigned short u16;
typedef float  f32x4 __attribute__((ext_vector_type(4)));
typedef u32    u32x4 __attribute__((ext_vector_type(4)));
typedef __bf16 bf16x8 __attribute__((ext_vector_type(8)));

// ---- workspace layout (float offsets) ----
constexpr size_t OFF_CNORM   = 0;                        // K
constexpr size_t OFF_IDX     = OFF_CNORM + K;            // N (int32)
constexpr size_t OFF_COUNTS  = OFF_IDX + N;              // K
constexpr size_t OFF_DW      = OFF_COUNTS + K;           // K*D
constexpr size_t OFF_SUMS    = OFF_DW + (size_t)K * D;   // 4 floats = 2 doubles
constexpr size_t OFF_FLAGCNT = OFF_SUMS + 4;             // 1 int
constexpr size_t OFF_FLAGLST = OFF_FLAGCNT + 1;          // N ints
constexpr size_t WS_FLOATS   = OFF_FLAGLST + N;

// ---- output layout (float offsets), reference return order ----
constexpr size_t OUT_ZQ   = 0;                          // N*D   (scratch: X2 bf16-split until scatter)
constexpr size_t OUT_IDX  = OUT_ZQ + (size_t)N * D;     // N
constexpr size_t OUT_LOSS = OUT_IDX + N;                // 1
constexpr size_t OUT_NCB  = OUT_LOSS + 1;               // K*D   (scratch: CB2 bf16-split until finalize)
constexpr size_t OUT_NCS  = OUT_NCB + (size_t)K * D;    // K
constexpr size_t OUT_EMA  = OUT_NCS + K;                // K*D

// ---------------------------------------------------------------------------
__device__ inline u16 f32_to_bf16_rne(float f)
{
    u32 u = __builtin_bit_cast(u32, f);
    u = (u + 0x7FFFu + ((u >> 16) & 1u)) >> 16;
    return (u16)u;
}

// split f32 -> interleaved (hi, lo) bf16 pairs; 1 float4 in -> 1 uint4 out
__global__ __launch_bounds__(256) void split_kernel(const float* __restrict__ src,
                                                    u32* __restrict__ dst)
{
    const size_t i = (size_t)blockIdx.x * 256 + threadIdx.x;
    const float4 v = ((const float4*)src)[i];
    u32x4 o;
    const float a[4] = {v.x, v.y, v.z, v.w};
#pragma unroll
    for (int j = 0; j < 4; ++j) {
        const u16 hi = f32_to_bf16_rne(a[j]);
        const float hif = __builtin_bit_cast(float, (u32)hi << 16);
        const u16 lo = f32_to_bf16_rne(a[j] - hif);
        ((u32*)&o)[j] = (u32)hi | ((u32)lo << 16);   // memory order: [hi, lo]
    }
    ((u32x4*)dst)[i] = o;
}

// ---------------------------------------------------------------------------
__global__ __launch_bounds__(256) void row_norm_kernel(const float* __restrict__ a,
                                                       float* __restrict__ out)
{
    const int row  = blockIdx.x * 4 + (threadIdx.x >> 6);
    const int lane = threadIdx.x & 63;
    const float4* r = (const float4*)(a + (size_t)row * D);
    const float4 v0 = r[lane];
    const float4 v1 = r[lane + 64];
    float s = v0.x * v0.x + v0.y * v0.y + v0.z * v0.z + v0.w * v0.w
            + v1.x * v1.x + v1.y * v1.y + v1.z * v1.z + v1.w * v1.w;
#pragma unroll
    for (int m = 32; m >= 1; m >>= 1) s += __shfl_xor(s, m, 64);
    if (lane == 0) out[row] = s;
}

// ---------------------------------------------------------------------------
// MFMA argmin. Block: 512 thr (8 waves), 128 points shared, 512 codes/chunk
// (64 per wave). A-operand = codes (M), B-operand = points (N). Per k-step:
// mfma(a,b) + mfma(swap16(a),b) = full f32-split product.
constexpr int BP = 128, BC = 512, KI = 32, NSTEP = 1024 / KI, NCHUNK = K / BC;
constexpr int CELEMS = BC * KI;            // 16384 u16
constexpr int XELEMS = BP * KI;            // 4096 u16
constexpr int BUF_ELEMS = CELEMS + XELEMS; // 40KB per buffer

__global__ __launch_bounds__(512, 2) void argmin_mfma_kernel(
    const u16* __restrict__ CB2, const u16* __restrict__ X2,
    const float* __restrict__ cnorm,
    int* __restrict__ idx_i, float* __restrict__ idx_f,
    int* __restrict__ flag_cnt, int* __restrict__ flag_list)
{
    __shared__ u16 lds[2][BUF_ELEMS];

    const int tid  = threadIdx.x;
    const int w    = tid >> 6;
    const int lane = tid & 63;
    const int l15  = lane & 15;
    const int lhi  = lane >> 4;          // 0..3
    const int n0   = blockIdx.x * BP;

    // fragment LDS elem offsets (within a buffer)
    const int cfrag_base = (w * 64 + l15) * KI + lhi * 8;   // + cg*16*KI
    const int xfrag_base = CELEMS + l15 * KI + lhi * 8;     // + p*16*KI

    auto stage = [&](u16* bufp, int chunk, int s) {
        const size_t cb_base = (size_t)chunk * BC * 1024 + (size_t)s * KI;
#pragma unroll
        for (int j = 0; j < 4; ++j) {
            const int slot = j * 512 + tid;
            const u16* g = CB2 + cb_base + (size_t)(slot >> 2) * 1024 + (slot & 3) * 8;
            u16* d = bufp + slot * 8;
            __builtin_amdgcn_global_load_lds((const __attribute__((address_space(1))) u32*)g,
                                             (__attribute__((address_space(3))) u32*)d, 16, 0, 0);
        }
        const u16* gx = X2 + (size_t)(n0 + (tid >> 2)) * 1024 + (tid & 3) * 8 + (size_t)s * KI;
        u16* dx = bufp + CELEMS + tid * 8;
        __builtin_amdgcn_global_load_lds((const __attribute__((address_space(1))) u32*)gx,
                                         (__attribute__((address_space(3))) u32*)dx, 16, 0, 0);
    };

    float b1[8], b2[8]; int i1[8];
#pragma unroll
    for (int p = 0; p < 8; ++p) { b1[p] = INFINITY; b2[p] = INFINITY; i1[p] = 0; }

    for (int chunk = 0; chunk < NCHUNK; ++chunk) {
        f32x4 acc[4][8];
        const f32x4 zero = {0.f, 0.f, 0.f, 0.f};
#pragma unroll
        for (int cg = 0; cg < 4; ++cg)
#pragma unroll
            for (int p = 0; p < 8; ++p) acc[cg][p] = zero;

        stage(&lds[0][0], chunk, 0);
        __syncthreads();

#pragma unroll 2
        for (int s = 0; s < NSTEP; ++s) {
            const u16* curb = (s & 1) ? &lds[1][0] : &lds[0][0];
            u16* nxtb       = (s & 1) ? &lds[0][0] : &lds[1][0];
            if (s + 1 < NSTEP) stage(nxtb, chunk, s + 1);

            u32x4 bfr[8];
#pragma unroll
            for (int p = 0; p < 8; ++p)
                bfr[p] = *(const u32x4*)(curb + xfrag_base + p * 16 * KI);
#pragma unroll
            for (int cg = 0; cg < 4; ++cg) {
                const u32x4 af = *(const u32x4*)(curb + cfrag_base + cg * 16 * KI);
                u32x4 as;
                as.x = (af.x >> 16) | (af.x << 16);
                as.y = (af.y >> 16) | (af.y << 16);
                as.z = (af.z >> 16) | (af.z << 16);
                as.w = (af.w >> 16) | (af.w << 16);
#pragma unroll
                for (int p = 0; p < 8; ++p) {
                    acc[cg][p] = __builtin_amdgcn_mfma_f32_16x16x32_bf16(
                        __builtin_bit_cast(bf16x8, af), __builtin_bit_cast(bf16x8, bfr[p]),
                        acc[cg][p], 0, 0, 0);
                    acc[cg][p] = __builtin_amdgcn_mfma_f32_16x16x32_bf16(
                        __builtin_bit_cast(bf16x8, as), __builtin_bit_cast(bf16x8, bfr[p]),
                        acc[cg][p], 0, 0, 0);
                }
            }
            __syncthreads();
        }

        // epilogue: dist = cn - 2*dot; running (best, 2nd-best, idx), codes ascending
        const int cb0 = chunk * BC + w * 64;
#pragma unroll
        for (int cg = 0; cg < 4; ++cg) {
            const int code0 = cb0 + cg * 16 + lhi * 4;
            const float c0 = cnorm[code0 + 0], c1 = cnorm[code0 + 1];
            const float c2 = cnorm[code0 + 2], c3 = cnorm[code0 + 3];
#pragma unroll
            for (int p = 0; p < 8; ++p) {
                const f32x4 A = acc[cg][p];
                const float dv[4] = {c0 - 2.f * A.x, c1 - 2.f * A.y,
                                     c2 - 2.f * A.z, c3 - 2.f * A.w};
#pragma unroll
                for (int r = 0; r < 4; ++r) {
                    if (dv[r] < b1[p]) { b2[p] = b1[p]; b1[p] = dv[r]; i1[p] = code0 + r; }
                    else if (dv[r] < b2[p]) { b2[p] = dv[r]; }
                }
            }
        }
    }

    // cross-lane merge (lanes {p, p+16, p+32, p+48} hold same point's candidates)
#pragma unroll
    for (int p = 0; p < 8; ++p) {
#pragma unroll
        for (int m = 16; m <= 32; m <<= 1) {
            const float ob1 = __shfl_xor(b1[p], m, 64);
            const float ob2 = __shfl_xor(b2[p], m, 64);
            const int   oi1 = __shfl_xor(i1[p], m, 64);
            const float nb2 = fminf(fminf(b2[p], ob2), fmaxf(b1[p], ob1));
            if (ob1 < b1[p] || (ob1 == b1[p] && oi1 < i1[p])) { b1[p] = ob1; i1[p] = oi1; }
            b2[p] = nb2;
        }
    }

    // cross-wave merge via LDS
    float* mb1 = (float*)&lds[0][0];
    float* mb2 = mb1 + 8 * BP;
    int*   mi  = (int*)(mb2 + 8 * BP);
    if (lane < 16) {
#pragma unroll
        for (int p = 0; p < 8; ++p) {
            const int pt = p * 16 + lane;
            mb1[w * BP + pt] = b1[p];
            mb2[w * BP + pt] = b2[p];
            mi [w * BP + pt] = i1[p];
        }
    }
    __syncthreads();
    if (tid < BP) {
        float fb1 = INFINITY, fb2 = INFINITY; int fi = 0;
        for (int ww = 0; ww < 8; ++ww) {
            const float a1 = mb1[ww * BP + tid], a2 = mb2[ww * BP + tid];
            const int   ai = mi[ww * BP + tid];
            const float nb2 = fminf(fminf(fb2, a2), fmaxf(fb1, a1));
            if (a1 < fb1 || (a1 == fb1 && ai < fi)) { fb1 = a1; fi = ai; }
            fb2 = nb2;
        }
        const int n = n0 + tid;
        idx_i[n] = fi;
        idx_f[n] = (float)fi;
        if (fb2 - fb1 < TAU) {
            const int pos = atomicAdd(flag_cnt, 1);
            flag_list[pos] = n;
        }
    }
}

// ---------------------------------------------------------------------------
// exact f32 re-scan for flagged (small-gap) points
__global__ __launch_bounds__(256) void exact_kernel(
    const float* __restrict__ x, const float* __restrict__ cb,
    const float* __restrict__ cnorm, const int* __restrict__ flag_cnt,
    const int* __restrict__ flag_list, int* __restrict__ idx_i, float* __restrict__ idx_f)
{
    __shared__ float4 xs[D / 4];
    __shared__ float rbv[256];
    __shared__ int   rbi[256];
    const int cnt = *flag_cnt;
    for (int i = blockIdx.x; i < cnt; i += gridDim.x) {
        const int n = flag_list[i];
        __syncthreads();
        for (int d = threadIdx.x; d < D / 4; d += 256)
            xs[d] = ((const float4*)(x + (size_t)n * D))[d];
        __syncthreads();
        float best = INFINITY; int besti = 0;
        for (int k = threadIdx.x; k < K; k += 256) {
            const float4* c4 = (const float4*)(cb + (size_t)k * D);
            float a0 = 0.f, a1 = 0.f, a2 = 0.f, a3 = 0.f;
            for (int d = 0; d < D / 4; ++d) {
                const float4 xv = xs[d], cv = c4[d];
                a0 = fmaf(xv.x, cv.x, a0);
                a1 = fmaf(xv.y, cv.y, a1);
                a2 = fmaf(xv.z, cv.z, a2);
                a3 = fmaf(xv.w, cv.w, a3);
            }
            const float dist = cnorm[k] - 2.0f * ((a0 + a1) + (a2 + a3));
            if (dist < best) { best = dist; besti = k; }
        }
        rbv[threadIdx.x] = best; rbi[threadIdx.x] = besti;
        __syncthreads();
        for (int off = 128; off > 0; off >>= 1) {
            if (threadIdx.x < off) {
                const float ov = rbv[threadIdx.x + off];
                const int   oi = rbi[threadIdx.x + off];
                if (ov < rbv[threadIdx.x] ||
                    (ov == rbv[threadIdx.x] && oi < rbi[threadIdx.x])) {
                    rbv[threadIdx.x] = ov; rbi[threadIdx.x] = oi;
                }
            }
            __syncthreads();
        }
        if (threadIdx.x == 0) { idx_i[n] = rbi[0]; idx_f[n] = (float)rbi[0]; }
        __syncthreads();
    }
}

// ---------------------------------------------------------------------------
__global__ __launch_bounds__(256) void scatter_kernel(
    const float* __restrict__ x, const float* __restrict__ cb,
    const int* __restrict__ idx_i, float* __restrict__ zq,
    float* __restrict__ counts, float* __restrict__ dw,
    double* __restrict__ loss_sum)
{
    const int n = blockIdx.x;
    const int k = idx_i[n];
    const int t = threadIdx.x;
    const size_t xoff = (size_t)n * D + t * 2;
    const size_t coff = (size_t)k * D + t * 2;

    const float2 xv = *(const float2*)(x + xoff);
    const float2 qv = *(const float2*)(cb + coff);
    *(float2*)(zq + xoff) = qv;

    const float dx = xv.x - qv.x, dy = xv.y - qv.y;
    float sq = dx * dx + dy * dy;

    atomicAdd(&dw[coff], xv.x);
    atomicAdd(&dw[coff + 1], xv.y);

#pragma unroll
    for (int m = 32; m >= 1; m >>= 1) sq += __shfl_xor(sq, m, 64);
    __shared__ float partial[4];
    if ((t & 63) == 0) partial[t >> 6] = sq;
    __syncthreads();
    if (t == 0) {
        atomicAdd(loss_sum, (double)(partial[0] + partial[1] + partial[2] + partial[3]));
        atomicAdd(&counts[k], 1.0f);
    }
}

// ---------------------------------------------------------------------------
__global__ __launch_bounds__(256) void csize_kernel(
    const float* __restrict__ csz, const float* __restrict__ counts,
    float* __restrict__ ncs, double* __restrict__ n_sum)
{
    const int k = blockIdx.x * 256 + threadIdx.x;
    const float v = DECAYF * csz[k] + OMDECAY * counts[k];
    ncs[k] = v;
    float s = v;
#pragma unroll
    for (int m = 32; m >= 1; m >>= 1) s += __shfl_xor(s, m, 64);
    __shared__ float partial[4];
    if ((threadIdx.x & 63) == 0) partial[threadIdx.x >> 6] = s;
    __syncthreads();
    if (threadIdx.x == 0)
        atomicAdd(n_sum, (double)(partial[0] + partial[1] + partial[2] + partial[3]));
}

// ---------------------------------------------------------------------------
__global__ __launch_bounds__(256) void finalize_kernel(
    const float* __restrict__ ema_w, const float* __restrict__ dw,
    const float* __restrict__ ncs, const double* __restrict__ n_sum,
    float* __restrict__ new_ema, float* __restrict__ new_cb)
{
    const int k = blockIdx.x;
    const float n = (float)n_sum[0];
    const float csm = (ncs[k] + EPSF) / (n + KEPSF) * n;
    const size_t base = (size_t)k * D + threadIdx.x * 2;

    const float2 e = *(const float2*)(ema_w + base);
    const float2 wv = *(const float2*)(dw + base);
    float2 ne;
    ne.x = DECAYF * e.x + OMDECAY * wv.x;
    ne.y = DECAYF * e.y + OMDECAY * wv.y;
    *(float2*)(new_ema + base) = ne;
    float2 nc;
    nc.x = ne.x / csm;
    nc.y = ne.y / csm;
    *(float2*)(new_cb + base) = nc;
}

// ---------------------------------------------------------------------------
__global__ void loss_kernel(const double* __restrict__ loss_sum, float* __restrict__ out_loss)
{
    out_loss[0] = (float)(1.25 * (loss_sum[0] / (double)((size_t)N * D)));
}

// ---------------------------------------------------------------------------
extern "C" void kernel_launch(void* const* d_in, const int* in_sizes, int n_in,
                              void* d_out, int out_size, void* d_ws, size_t ws_size,
                              hipStream_t stream)
{
    const float* z_e   = (const float*)d_in[0];
    const float* cbook = (const float*)d_in[1];
    const float* csz   = (const float*)d_in[2];
    const float* ema_w = (const float*)d_in[3];

    float* out = (float*)d_out;
    float* ws  = (float*)d_ws;

    float*  cnorm     = ws + OFF_CNORM;
    int*    idx_i     = (int*)(ws + OFF_IDX);
    float*  counts    = ws + OFF_COUNTS;
    float*  dw        = ws + OFF_DW;
    double* loss_sum  = (double*)(ws + OFF_SUMS);
    double* n_sum     = loss_sum + 1;
    int*    flag_cnt  = (int*)(ws + OFF_FLAGCNT);
    int*    flag_list = (int*)(ws + OFF_FLAGLST);

    // bf16-split scratch lives in d_out regions later overwritten:
    u16* X2  = (u16*)(out + OUT_ZQ);    // [N][1024] — overwritten by scatter (zq)
    u16* CB2 = (u16*)(out + OUT_NCB);   // [K][1024] — overwritten by finalize (new_cb)

    // zero accumulators: counts, dw, sums, flag_cnt
    hipMemsetAsync(counts, 0, (OFF_FLAGCNT + 1 - OFF_COUNTS) * sizeof(float), stream);

    split_kernel<<<(int)((size_t)N * D / 4 / 256), 256, 0, stream>>>(z_e, (u32*)X2);
    split_kernel<<<(int)((size_t)K * D / 4 / 256), 256, 0, stream>>>(cbook, (u32*)CB2);
    row_norm_kernel<<<K / 4, 256, 0, stream>>>(cbook, cnorm);

    argmin_mfma_kernel<<<N / BP, 512, 0, stream>>>(CB2, X2, cnorm, idx_i,
                                                   out + OUT_IDX, flag_cnt, flag_list);

    exact_kernel<<<64, 256, 0, stream>>>(z_e, cbook, cnorm, flag_cnt, flag_list,
                                         idx_i, out + OUT_IDX);

    scatter_kernel<<<N, 256, 0, stream>>>(z_e, cbook, idx_i, out + OUT_ZQ,
                                          counts, dw, loss_sum);

    csize_kernel<<<K / 256, 256, 0, stream>>>(csz, counts, out + OUT_NCS, n_sum);

    finalize_kernel<<<K, 256, 0, stream>>>(ema_w, dw, out + OUT_NCS, n_sum,
                                           out + OUT_EMA, out + OUT_NCB);

    loss_kernel<<<1, 1, 0, stream>>>(loss_sum, out + OUT_LOSS);
}

// Round 6
// 1687.490 us; speedup vs baseline: 3.4744x; 1.1086x over previous
//
#include <hip/hip_runtime.h>

// VQ-VAE EMA vector quantizer, MI355X.
// R6 = R5 + ONE fix: 8-byte-align OFF_SUMS. R3-R5 aborts were
// global_atomic_add_f64 on a misaligned double (OFF_SUMS was an odd word
// offset after R3's layout reshuffle: OFF_OFFS holds K+1=8193 entries).
// Argmin: R2's proven 2-buffer __syncthreads discipline + fragment-order LDS
// (conflict-free ds_read_b128). Scatter: inverted-list (no f32 atomics on dw).

constexpr int N = 32768;   // B*L
constexpr int D = 512;
constexpr int K = 8192;

constexpr float DECAYF  = 0.99f;
constexpr float OMDECAY = (float)(1.0 - 0.99);
constexpr float EPSF    = 1e-6f;
constexpr float KEPSF   = (float)(8192 * 1e-6);
constexpr float TAU     = 0.02f;   // gap threshold for exact re-check

typedef unsigned int   u32;
typedef unsigned short u16;
typedef float  f32x4 __attribute__((ext_vector_type(4)));
typedef u32    u32x4 __attribute__((ext_vector_type(4)));
typedef __bf16 bf16x8 __attribute__((ext_vector_type(8)));

// ---- workspace layout (32-bit word offsets) ----
constexpr size_t OFF_CNORM   = 0;                        // K floats
constexpr size_t OFF_IDX     = OFF_CNORM + K;            // N int        = 8192
constexpr size_t OFF_CNTI    = OFF_IDX + N;              // K int        = 40960
constexpr size_t OFF_NEXT    = OFF_CNTI + K;             // K int        = 49152
constexpr size_t OFF_OFFS    = OFF_NEXT + K;             // K+1 int      = 57344
constexpr size_t OFF_LIST    = OFF_OFFS + K + 2;         // N int (pad->even) = 65538
constexpr size_t OFF_SUMS    = OFF_LIST + N;             // 4 words = 2 doubles = 98306 (EVEN: f64-atomic safe)
constexpr size_t OFF_FLAGC   = OFF_SUMS + 4;             // 1 int
constexpr size_t OFF_FLAGL   = OFF_FLAGC + 1;            // N int
static_assert((OFF_SUMS & 1) == 0, "loss_sum/n_sum must be 8-byte aligned");

// ---- output layout (float offsets), reference return order ----
constexpr size_t OUT_ZQ   = 0;                          // N*D (scratch: X2 until zq_loss)
constexpr size_t OUT_IDX  = OUT_ZQ + (size_t)N * D;     // N
constexpr size_t OUT_LOSS = OUT_IDX + N;                // 1
constexpr size_t OUT_NCB  = OUT_LOSS + 1;               // K*D (scratch: CB2 until finalize)
constexpr size_t OUT_NCS  = OUT_NCB + (size_t)K * D;    // K
constexpr size_t OUT_EMA  = OUT_NCS + K;                // K*D

// ---------------------------------------------------------------------------
__device__ inline u16 f32_to_bf16_rne(float f)
{
    u32 u = __builtin_bit_cast(u32, f);
    u = (u + 0x7FFFu + ((u >> 16) & 1u)) >> 16;
    return (u16)u;
}

// split f32 -> (hi,lo) bf16 pairs written in MFMA FRAGMENT ORDER:
// out elem ((R*32+S)*64 + l)*8 + j2 holds M[R*16+(l&15)][k = S*32+(l>>4)*8+j2],
// with k=2d -> hi(d), k=2d+1 -> lo(d). Verified: d = S*16+(l>>4)*4+j == 4c+j.
__global__ __launch_bounds__(256) void split_frag_kernel(const float* __restrict__ src,
                                                         u32* __restrict__ dst)
{
    const size_t t = (size_t)blockIdx.x * 256 + threadIdx.x;
    const int row = (int)(t >> 7);        // source row (128 float4 per row)
    const int c   = (int)(t & 127);       // float4 col
    const float4 v = ((const float4*)src)[t];
    const int S = c >> 2;
    const int l = ((c & 3) << 4) | (row & 15);
    const int R = row >> 4;
    u32x4 o;
    const float a[4] = {v.x, v.y, v.z, v.w};
#pragma unroll
    for (int j = 0; j < 4; ++j) {
        const u16 hi = f32_to_bf16_rne(a[j]);
        const float hif = __builtin_bit_cast(float, (u32)hi << 16);
        const u16 lo = f32_to_bf16_rne(a[j] - hif);
        ((u32*)&o)[j] = (u32)hi | ((u32)lo << 16);
    }
    const size_t ou32 = (((size_t)R * 32 + S) * 64 + l) * 4;
    *(u32x4*)(dst + ou32) = o;
}

// ---------------------------------------------------------------------------
__global__ __launch_bounds__(256) void row_norm_kernel(const float* __restrict__ a,
                                                       float* __restrict__ out)
{
    const int row  = blockIdx.x * 4 + (threadIdx.x >> 6);
    const int lane = threadIdx.x & 63;
    const float4* r = (const float4*)(a + (size_t)row * D);
    const float4 v0 = r[lane];
    const float4 v1 = r[lane + 64];
    float s = v0.x * v0.x + v0.y * v0.y + v0.z * v0.z + v0.w * v0.w
            + v1.x * v1.x + v1.y * v1.y + v1.z * v1.z + v1.w * v1.w;
#pragma unroll
    for (int m = 32; m >= 1; m >>= 1) s += __shfl_xor(s, m, 64);
    if (lane == 0) out[row] = s;
}

// ---------------------------------------------------------------------------
// MFMA argmin. 512 thr (8 waves), 128 points/block, 512-code chunks (64/wave).
// Double-buffer + __syncthreads per step; fragment-order LDS so every
// ds_read_b128 is base + lane*16B (conflict-free).
constexpr int BP = 128, BC = 512, KI = 32;
constexpr int NSTEP = 1024 / KI, NCHUNK = K / BC;   // 32, 16
constexpr int CELEMS = BC * KI;            // 16384 u16 (32KB)
constexpr int XELEMS = BP * KI;            // 4096 u16 (8KB)
constexpr int BUFE = CELEMS + XELEMS;      // 20480 u16 (40KB)

__global__ __launch_bounds__(512, 2) void argmin_mfma_kernel(
    const u16* __restrict__ CB2, const u16* __restrict__ X2,
    const float* __restrict__ cnorm,
    int* __restrict__ idx_i, float* __restrict__ idx_f,
    int* __restrict__ flag_cnt, int* __restrict__ flag_list)
{
    __shared__ __align__(16) u16 lds[2][BUFE];     // 80 KB

    const int tid  = threadIdx.x;
    const int w    = tid >> 6;
    const int lane = tid & 63;
    const int lhi  = lane >> 4;
    const int n0   = blockIdx.x * BP;

    auto stage = [&](u16* bufp, int chunk, int s) {
#pragma unroll
        for (int j = 0; j < 4; ++j) {
            const int slot = j * 512 + tid;
            const u16* gsrc = CB2 + (((size_t)(chunk * 32 + (slot >> 6)) * 32 + s) * 512
                                     + (slot & 63) * 8);
            u16* d = bufp + slot * 8;
            __builtin_amdgcn_global_load_lds((const __attribute__((address_space(1))) u32*)gsrc,
                                             (__attribute__((address_space(3))) u32*)d, 16, 0, 0);
        }
        const u16* gx = X2 + (((size_t)(n0 / 16 + (tid >> 6)) * 32 + s) * 512
                              + (tid & 63) * 8);
        u16* dx = bufp + CELEMS + tid * 8;
        __builtin_amdgcn_global_load_lds((const __attribute__((address_space(1))) u32*)gx,
                                         (__attribute__((address_space(3))) u32*)dx, 16, 0, 0);
    };

    float b1[8], b2[8]; int i1[8];
#pragma unroll
    for (int p = 0; p < 8; ++p) { b1[p] = INFINITY; b2[p] = INFINITY; i1[p] = 0; }

    for (int chunk = 0; chunk < NCHUNK; ++chunk) {
        f32x4 acc[4][8];
        const f32x4 zero = {0.f, 0.f, 0.f, 0.f};
#pragma unroll
        for (int cg = 0; cg < 4; ++cg)
#pragma unroll
            for (int p = 0; p < 8; ++p) acc[cg][p] = zero;

        stage(&lds[0][0], chunk, 0);
        __syncthreads();

#pragma unroll 2
        for (int s = 0; s < NSTEP; ++s) {
            const u16* cur = (s & 1) ? &lds[1][0] : &lds[0][0];
            u16* nxt       = (s & 1) ? &lds[0][0] : &lds[1][0];
            if (s + 1 < NSTEP) stage(nxt, chunk, s + 1);

            u32x4 bfr[8];
#pragma unroll
            for (int p = 0; p < 8; ++p)
                bfr[p] = *(const u32x4*)(cur + CELEMS + p * 512 + lane * 8);
#pragma unroll
            for (int cg = 0; cg < 4; ++cg) {
                const u32x4 af = *(const u32x4*)(cur + (w * 4 + cg) * 512 + lane * 8);
                u32x4 as;
                as.x = (af.x >> 16) | (af.x << 16);
                as.y = (af.y >> 16) | (af.y << 16);
                as.z = (af.z >> 16) | (af.z << 16);
                as.w = (af.w >> 16) | (af.w << 16);
#pragma unroll
                for (int p = 0; p < 8; ++p) {
                    acc[cg][p] = __builtin_amdgcn_mfma_f32_16x16x32_bf16(
                        __builtin_bit_cast(bf16x8, af), __builtin_bit_cast(bf16x8, bfr[p]),
                        acc[cg][p], 0, 0, 0);
                    acc[cg][p] = __builtin_amdgcn_mfma_f32_16x16x32_bf16(
                        __builtin_bit_cast(bf16x8, as), __builtin_bit_cast(bf16x8, bfr[p]),
                        acc[cg][p], 0, 0, 0);
                }
            }
            __syncthreads();
        }

        // chunk epilogue: dist = cn - 2*dot; running (best, 2nd), codes ascending
        const int cb0 = chunk * BC + w * 64;
#pragma unroll
        for (int cg = 0; cg < 4; ++cg) {
            const int code0 = cb0 + cg * 16 + lhi * 4;
            const float4 cn4 = *(const float4*)(cnorm + code0);
            const float cn[4] = {cn4.x, cn4.y, cn4.z, cn4.w};
#pragma unroll
            for (int p = 0; p < 8; ++p) {
                const f32x4 A = acc[cg][p];
                const float dv[4] = {cn[0] - 2.f * A.x, cn[1] - 2.f * A.y,
                                     cn[2] - 2.f * A.z, cn[3] - 2.f * A.w};
#pragma unroll
                for (int r = 0; r < 4; ++r) {
                    if (dv[r] < b1[p]) { b2[p] = b1[p]; b1[p] = dv[r]; i1[p] = code0 + r; }
                    else if (dv[r] < b2[p]) { b2[p] = dv[r]; }
                }
            }
        }
    }

    // cross-lane merge (lanes {p, p+16, p+32, p+48} hold same point's candidates)
#pragma unroll
    for (int p = 0; p < 8; ++p) {
#pragma unroll
        for (int m = 16; m <= 32; m <<= 1) {
            const float ob1 = __shfl_xor(b1[p], m, 64);
            const float ob2 = __shfl_xor(b2[p], m, 64);
            const int   oi1 = __shfl_xor(i1[p], m, 64);
            const float nb2 = fminf(fminf(b2[p], ob2), fmaxf(b1[p], ob1));
            if (ob1 < b1[p] || (ob1 == b1[p] && oi1 < i1[p])) { b1[p] = ob1; i1[p] = oi1; }
            b2[p] = nb2;
        }
    }

    __syncthreads();

    float* mb1 = (float*)&lds[0][0];
    float* mb2 = mb1 + 8 * BP;
    int*   mi  = (int*)(mb2 + 8 * BP);
    if (lane < 16) {
#pragma unroll
        for (int p = 0; p < 8; ++p) {
            const int pt = p * 16 + lane;
            mb1[w * BP + pt] = b1[p];
            mb2[w * BP + pt] = b2[p];
            mi [w * BP + pt] = i1[p];
        }
    }
    __syncthreads();
    if (tid < BP) {
        float fb1 = INFINITY, fb2 = INFINITY; int fi = 0;
        for (int ww = 0; ww < 8; ++ww) {
            const float a1 = mb1[ww * BP + tid], a2 = mb2[ww * BP + tid];
            const int   ai = mi[ww * BP + tid];
            const float nb2 = fminf(fminf(fb2, a2), fmaxf(fb1, a1));
            if (a1 < fb1 || (a1 == fb1 && ai < fi)) { fb1 = a1; fi = ai; }
            fb2 = nb2;
        }
        const int n = n0 + tid;
        idx_i[n] = fi;
        idx_f[n] = (float)fi;
        if (fb2 - fb1 < TAU) {
            const int pos = atomicAdd(flag_cnt, 1);
            if ((unsigned)pos < (unsigned)N) flag_list[pos] = n;
        }
    }
}

// ---------------------------------------------------------------------------
// exact f32 re-scan for flagged (small-gap) points
__global__ __launch_bounds__(256) void exact_kernel(
    const float* __restrict__ x, const float* __restrict__ cb,
    const float* __restrict__ cnorm, const int* __restrict__ flag_cnt,
    const int* __restrict__ flag_list, int* __restrict__ idx_i, float* __restrict__ idx_f)
{
    __shared__ float4 xs[D / 4];
    __shared__ float rbv[256];
    __shared__ int   rbi[256];
    const int cnt = min(*flag_cnt, N);
    for (int i = blockIdx.x; i < cnt; i += gridDim.x) {
        const int n = flag_list[i] & (N - 1);
        __syncthreads();
        for (int d = threadIdx.x; d < D / 4; d += 256)
            xs[d] = ((const float4*)(x + (size_t)n * D))[d];
        __syncthreads();
        float best = INFINITY; int besti = 0;
        for (int k = threadIdx.x; k < K; k += 256) {
            const float4* c4 = (const float4*)(cb + (size_t)k * D);
            float a0 = 0.f, a1 = 0.f, a2 = 0.f, a3 = 0.f;
            for (int d = 0; d < D / 4; ++d) {
                const float4 xv = xs[d], cv = c4[d];
                a0 = fmaf(xv.x, cv.x, a0);
                a1 = fmaf(xv.y, cv.y, a1);
                a2 = fmaf(xv.z, cv.z, a2);
                a3 = fmaf(xv.w, cv.w, a3);
            }
            const float dist = cnorm[k] - 2.0f * ((a0 + a1) + (a2 + a3));
            if (dist < best) { best = dist; besti = k; }
        }
        rbv[threadIdx.x] = best; rbi[threadIdx.x] = besti;
        __syncthreads();
        for (int off = 128; off > 0; off >>= 1) {
            if (threadIdx.x < off) {
                const float ov = rbv[threadIdx.x + off];
                const int   oi = rbi[threadIdx.x + off];
                if (ov < rbv[threadIdx.x] ||
                    (ov == rbv[threadIdx.x] && oi < rbi[threadIdx.x])) {
                    rbv[threadIdx.x] = ov; rbi[threadIdx.x] = oi;
                }
            }
            __syncthreads();
        }
        if (threadIdx.x == 0) { idx_i[n] = rbi[0]; idx_f[n] = (float)rbi[0]; }
        __syncthreads();
    }
}

// ---------------------------------------------------------------------------
// zq gather + loss partials + integer counts (order-exact). 2 points/block.
__global__ __launch_bounds__(256) void zq_loss_kernel(
    const float* __restrict__ x, const float* __restrict__ cb,
    const int* __restrict__ idx_i, float* __restrict__ zq,
    int* __restrict__ cnti, double* __restrict__ loss_sum)
{
    const int sub = threadIdx.x >> 7;
    const int t   = threadIdx.x & 127;
    const int n   = blockIdx.x * 2 + sub;
    const int k   = idx_i[n] & (K - 1);   // clamp: poison-proof
    const size_t xoff = (size_t)n * 128 + t;
    const size_t coff = (size_t)k * 128 + t;

    const float4 xv = ((const float4*)x)[xoff];
    const float4 qv = ((const float4*)cb)[coff];
    ((float4*)zq)[xoff] = qv;

    const float d0 = xv.x - qv.x, d1 = xv.y - qv.y;
    const float d2 = xv.z - qv.z, d3 = xv.w - qv.w;
    float sq = d0 * d0 + d1 * d1 + d2 * d2 + d3 * d3;

    if (t == 0) atomicAdd(&cnti[k], 1);

#pragma unroll
    for (int m = 32; m >= 1; m >>= 1) sq += __shfl_xor(sq, m, 64);
    __shared__ float partial[4];
    if ((threadIdx.x & 63) == 0) partial[threadIdx.x >> 6] = sq;
    __syncthreads();
    if (threadIdx.x == 0)
        atomicAdd(loss_sum, (double)(partial[0] + partial[1] + partial[2] + partial[3]));
}

// ---------------------------------------------------------------------------
// single block: prefix-scan counts -> offsets/next, ncs = EMA counts, n_sum.
__global__ __launch_bounds__(256) void scan_kernel(
    const int* __restrict__ cnti, const float* __restrict__ csz,
    int* __restrict__ offs, int* __restrict__ nxt,
    float* __restrict__ ncs, double* __restrict__ n_sum)
{
    __shared__ int    tsum[256];
    __shared__ double dsum[256];
    const int t = threadIdx.x;
    const int base = t * 32;
    int s = 0;
    double dn = 0.0;
#pragma unroll
    for (int i = 0; i < 32; ++i) {
        const int c = cnti[base + i];
        s += c;
        const float v = DECAYF * csz[base + i] + OMDECAY * (float)c;
        ncs[base + i] = v;
        dn += (double)v;
    }
    tsum[t] = s; dsum[t] = dn;
    __syncthreads();
    int run = 0;
    for (int j = 0; j < t; ++j) run += tsum[j];
#pragma unroll
    for (int i = 0; i < 32; ++i) {
        offs[base + i] = run;
        nxt[base + i] = run;
        run += cnti[base + i];
    }
    if (t == 255) offs[K] = run;
    if (t == 0) {
        double tot = 0.0;
        for (int j = 0; j < 256; ++j) tot += dsum[j];
        n_sum[0] = tot;
    }
}

// ---------------------------------------------------------------------------
__global__ __launch_bounds__(256) void fill_kernel(
    const int* __restrict__ idx_i, int* __restrict__ nxt, int* __restrict__ list)
{
    const int p = blockIdx.x * 256 + threadIdx.x;
    const int k = idx_i[p] & (K - 1);
    const int pos = atomicAdd(&nxt[k], 1);
    if ((unsigned)pos < (unsigned)N) list[pos] = p;
}

// ---------------------------------------------------------------------------
// block per code: dw = sum of assigned points (gathered), fused EMA + finalize.
__global__ __launch_bounds__(128) void gather_finalize_kernel(
    const float* __restrict__ x, const int* __restrict__ offs,
    const int* __restrict__ list, const float* __restrict__ ema_w,
    const float* __restrict__ ncs, const double* __restrict__ n_sum,
    float* __restrict__ new_ema, float* __restrict__ new_cb)
{
    const int k = blockIdx.x;
    const int t = threadIdx.x;
    const int beg = min(offs[k], N), end = min(offs[k + 1], N);
    float4 acc = {0.f, 0.f, 0.f, 0.f};
    for (int i = beg; i < end; ++i) {
        const int p = list[i] & (N - 1);
        const float4 v = ((const float4*)x)[(size_t)p * 128 + t];
        acc.x += v.x; acc.y += v.y; acc.z += v.z; acc.w += v.w;
    }
    const float n = (float)n_sum[0];
    const float csm = (ncs[k] + EPSF) / (n + KEPSF) * n;
    const size_t o = (size_t)k * 128 + t;
    const float4 e = ((const float4*)ema_w)[o];
    float4 ne;
    ne.x = DECAYF * e.x + OMDECAY * acc.x;
    ne.y = DECAYF * e.y + OMDECAY * acc.y;
    ne.z = DECAYF * e.z + OMDECAY * acc.z;
    ne.w = DECAYF * e.w + OMDECAY * acc.w;
    ((float4*)new_ema)[o] = ne;
    float4 nc;
    nc.x = ne.x / csm; nc.y = ne.y / csm; nc.z = ne.z / csm; nc.w = ne.w / csm;
    ((float4*)new_cb)[o] = nc;
}

// ---------------------------------------------------------------------------
__global__ void loss_kernel(const double* __restrict__ loss_sum, float* __restrict__ out_loss)
{
    out_loss[0] = (float)(1.25 * (loss_sum[0] / (double)((size_t)N * D)));
}

// ---------------------------------------------------------------------------
extern "C" void kernel_launch(void* const* d_in, const int* in_sizes, int n_in,
                              void* d_out, int out_size, void* d_ws, size_t ws_size,
                              hipStream_t stream)
{
    const float* z_e   = (const float*)d_in[0];
    const float* cbook = (const float*)d_in[1];
    const float* csz   = (const float*)d_in[2];
    const float* ema_w = (const float*)d_in[3];

    float* out = (float*)d_out;
    u32*   ws  = (u32*)d_ws;

    float*  cnorm     = (float*)(ws + OFF_CNORM);
    int*    idx_i     = (int*)(ws + OFF_IDX);
    int*    cnti      = (int*)(ws + OFF_CNTI);
    int*    nxt       = (int*)(ws + OFF_NEXT);
    int*    offs      = (int*)(ws + OFF_OFFS);
    int*    list      = (int*)(ws + OFF_LIST);
    double* loss_sum  = (double*)(ws + OFF_SUMS);
    double* n_sum     = loss_sum + 1;
    int*    flag_cnt  = (int*)(ws + OFF_FLAGC);
    int*    flag_list = (int*)(ws + OFF_FLAGL);

    // bf16-split fragment-order scratch in d_out regions overwritten later:
    u16* X2  = (u16*)(out + OUT_ZQ);    // [N/16][32][64][8] — overwritten by zq_loss
    u16* CB2 = (u16*)(out + OUT_NCB);   // [K/16][32][64][8] — overwritten by finalize

    // zero accumulators: cnti .. flag_cnt (covers cnti, nxt, offs, list, sums, flagc)
    hipMemsetAsync(ws + OFF_CNTI, 0, (OFF_FLAGC + 1 - OFF_CNTI) * sizeof(u32), stream);

    split_frag_kernel<<<(size_t)N * 128 / 256, 256, 0, stream>>>(z_e, (u32*)X2);
    split_frag_kernel<<<(size_t)K * 128 / 256, 256, 0, stream>>>(cbook, (u32*)CB2);
    row_norm_kernel<<<K / 4, 256, 0, stream>>>(cbook, cnorm);

    argmin_mfma_kernel<<<N / BP, 512, 0, stream>>>(CB2, X2, cnorm, idx_i,
                                                   out + OUT_IDX, flag_cnt, flag_list);

    exact_kernel<<<64, 256, 0, stream>>>(z_e, cbook, cnorm, flag_cnt, flag_list,
                                         idx_i, out + OUT_IDX);

    zq_loss_kernel<<<N / 2, 256, 0, stream>>>(z_e, cbook, idx_i, out + OUT_ZQ,
                                              cnti, loss_sum);

    scan_kernel<<<1, 256, 0, stream>>>(cnti, csz, offs, nxt, out + OUT_NCS, n_sum);

    fill_kernel<<<N / 256, 256, 0, stream>>>(idx_i, nxt, list);

    gather_finalize_kernel<<<K, 128, 0, stream>>>(z_e, offs, list, ema_w,
                                                  out + OUT_NCS, n_sum,
                                                  out + OUT_EMA, out + OUT_NCB);

    loss_kernel<<<1, 1, 0, stream>>>(loss_sum, out + OUT_LOSS);
}

// Round 7
// 1506.949 us; speedup vs baseline: 3.8906x; 1.1198x over previous
//
#include <hip/hip_runtime.h>

// VQ-VAE EMA vector quantizer, MI355X.
// R7: (1) argmin = 3-buffer counted-vmcnt(5) pipeline + setprio (exonerated:
// R3-R5 aborts were a misaligned f64 atomic, fixed in R6); (2) zq_loss per-block
// loss partials (was 16K serialized f64 atomics on one address); (3) split with
// coalesced fragment-order writes. Fragment-order LDS: bank conflicts == 0 (R6).

constexpr int N = 32768;   // B*L
constexpr int D = 512;
constexpr int K = 8192;

constexpr float DECAYF  = 0.99f;
constexpr float OMDECAY = (float)(1.0 - 0.99);
constexpr float EPSF    = 1e-6f;
constexpr float KEPSF   = (float)(8192 * 1e-6);
constexpr float TAU     = 0.02f;   // gap threshold for exact re-check

typedef unsigned int   u32;
typedef unsigned short u16;
typedef float  f32x4 __attribute__((ext_vector_type(4)));
typedef u32    u32x4 __attribute__((ext_vector_type(4)));
typedef __bf16 bf16x8 __attribute__((ext_vector_type(8)));

// ---- workspace layout (32-bit word offsets) ----
constexpr size_t OFF_CNORM   = 0;                        // K floats
constexpr size_t OFF_IDX     = OFF_CNORM + K;            // N int
constexpr size_t OFF_CNTI    = OFF_IDX + N;              // K int
constexpr size_t OFF_NEXT    = OFF_CNTI + K;             // K int
constexpr size_t OFF_OFFS    = OFF_NEXT + K;             // K+1 int
constexpr size_t OFF_LIST    = OFF_OFFS + K + 2;         // N int (pad->even)
constexpr size_t OFF_SUMS    = OFF_LIST + N;             // 2 words = 1 double (n_sum), EVEN
constexpr size_t OFF_FLAGC   = OFF_SUMS + 2;             // 1 int
constexpr size_t OFF_FLAGL   = OFF_FLAGC + 1;            // N int
constexpr size_t OFF_LOSSP   = ((OFF_FLAGL + N + 1) & ~(size_t)1); // N/2 doubles, EVEN
static_assert((OFF_SUMS & 1) == 0, "n_sum must be 8-byte aligned");
static_assert((OFF_LOSSP & 1) == 0, "loss partials must be 8-byte aligned");

// ---- output layout (float offsets), reference return order ----
constexpr size_t OUT_ZQ   = 0;                          // N*D (scratch: X2 until zq_loss)
constexpr size_t OUT_IDX  = OUT_ZQ + (size_t)N * D;     // N
constexpr size_t OUT_LOSS = OUT_IDX + N;                // 1
constexpr size_t OUT_NCB  = OUT_LOSS + 1;               // K*D (scratch: CB2 until finalize)
constexpr size_t OUT_NCS  = OUT_NCB + (size_t)K * D;    // K
constexpr size_t OUT_EMA  = OUT_NCS + K;                // K*D

// ---------------------------------------------------------------------------
__device__ inline u16 f32_to_bf16_rne(float f)
{
    u32 u = __builtin_bit_cast(u32, f);
    u = (u + 0x7FFFu + ((u >> 16) & 1u)) >> 16;
    return (u16)u;
}

// split f32 -> (hi,lo) bf16 pairs in MFMA FRAGMENT ORDER, coalesced writes.
// Block owns rows [R*16, R*16+16). Wave w handles S = w, w+4, ..., w+28.
// Lane l: reads float4 (row R*16+(l&15), cols S*16+(l>>4)*4..+3), writes u32x4
// at frag slot ((R*32+S)*64+l) — consecutive lanes -> consecutive 16B. Same
// element mapping as R6 (d = S*16+(l>>4)*4+j; k=2d->hi, 2d+1->lo).
__global__ __launch_bounds__(256) void split_frag_kernel(const float* __restrict__ src,
                                                         u32x4* __restrict__ dst)
{
    const int R = blockIdx.x;
    const int w = threadIdx.x >> 6;
    const int l = threadIdx.x & 63;
    const int row = R * 16 + (l & 15);
    const int cq  = l >> 4;
#pragma unroll
    for (int i = 0; i < 8; ++i) {
        const int S = w + 4 * i;
        const float4 v = ((const float4*)src)[(size_t)row * 128 + S * 4 + cq];
        u32x4 o;
        const float a[4] = {v.x, v.y, v.z, v.w};
#pragma unroll
        for (int j = 0; j < 4; ++j) {
            const u16 hi = f32_to_bf16_rne(a[j]);
            const float hif = __builtin_bit_cast(float, (u32)hi << 16);
            const u16 lo = f32_to_bf16_rne(a[j] - hif);
            ((u32*)&o)[j] = (u32)hi | ((u32)lo << 16);
        }
        dst[((size_t)R * 32 + S) * 64 + l] = o;
    }
}

// ---------------------------------------------------------------------------
__global__ __launch_bounds__(256) void row_norm_kernel(const float* __restrict__ a,
                                                       float* __restrict__ out)
{
    const int row  = blockIdx.x * 4 + (threadIdx.x >> 6);
    const int lane = threadIdx.x & 63;
    const float4* r = (const float4*)(a + (size_t)row * D);
    const float4 v0 = r[lane];
    const float4 v1 = r[lane + 64];
    float s = v0.x * v0.x + v0.y * v0.y + v0.z * v0.z + v0.w * v0.w
            + v1.x * v1.x + v1.y * v1.y + v1.z * v1.z + v1.w * v1.w;
#pragma unroll
    for (int m = 32; m >= 1; m >>= 1) s += __shfl_xor(s, m, 64);
    if (lane == 0) out[row] = s;
}

// ---------------------------------------------------------------------------
// MFMA argmin. 512 thr (8 waves), 128 points/block, 512-code chunks (64/wave).
// Fragment-order LDS (0 bank conflicts), 3-buffer counted-vmcnt(5) pipeline:
// stage(g+2) issued at iter g; vmcnt(5) at iter end retires stage(g+1) (5 loads
// per stage, <=10 outstanding). Cross-wave WAR safe: each wave's ds_reads of
// buf b are consumed by its MFMAs before it reaches the next barrier, and the
// restage of b is issued only after that barrier.
constexpr int BP = 128, BC = 512, KI = 32;
constexpr int NSTEP = 1024 / KI, NCHUNK = K / BC, TOTAL = NCHUNK * NSTEP; // 32,16,512
constexpr int CELEMS = BC * KI;            // 16384 u16 (32KB)
constexpr int XELEMS = BP * KI;            // 4096 u16 (8KB)
constexpr int BUFE = CELEMS + XELEMS;      // 20480 u16 (40KB)

__global__ __launch_bounds__(512, 2) void argmin_mfma_kernel(
    const u16* __restrict__ CB2, const u16* __restrict__ X2,
    const float* __restrict__ cnorm,
    int* __restrict__ idx_i, float* __restrict__ idx_f,
    int* __restrict__ flag_cnt, int* __restrict__ flag_list)
{
    __shared__ __align__(16) u16 lds[3 * BUFE];    // 120 KB

    const int tid  = threadIdx.x;
    const int w    = tid >> 6;
    const int lane = tid & 63;
    const int lhi  = lane >> 4;
    const int n0   = blockIdx.x * BP;

    auto stage = [&](int g) {
        u16* bufp = &lds[(g % 3) * BUFE];
        const int c = g >> 5, s = g & 31;
#pragma unroll
        for (int j = 0; j < 4; ++j) {
            const int slot = j * 512 + tid;
            const u16* gsrc = CB2 + (((size_t)(c * 32 + (slot >> 6)) * 32 + s) * 512
                                     + (slot & 63) * 8);
            u16* d = bufp + slot * 8;
            __builtin_amdgcn_global_load_lds((const __attribute__((address_space(1))) u32*)gsrc,
                                             (__attribute__((address_space(3))) u32*)d, 16, 0, 0);
        }
        const u16* gx = X2 + (((size_t)(n0 / 16 + (tid >> 6)) * 32 + s) * 512
                              + (tid & 63) * 8);
        u16* dx = bufp + CELEMS + tid * 8;
        __builtin_amdgcn_global_load_lds((const __attribute__((address_space(1))) u32*)gx,
                                         (__attribute__((address_space(3))) u32*)dx, 16, 0, 0);
    };

    float b1[8], b2[8]; int i1[8];
#pragma unroll
    for (int p = 0; p < 8; ++p) { b1[p] = INFINITY; b2[p] = INFINITY; i1[p] = 0; }

    f32x4 acc[4][8];
    const f32x4 zero = {0.f, 0.f, 0.f, 0.f};
#pragma unroll
    for (int cg = 0; cg < 4; ++cg)
#pragma unroll
        for (int p = 0; p < 8; ++p) acc[cg][p] = zero;

    stage(0);
    stage(1);
    asm volatile("s_waitcnt vmcnt(5)" ::: "memory");   // stage(0) landed

    for (int g = 0; g < TOTAL; ++g) {
        __builtin_amdgcn_s_barrier();
        __builtin_amdgcn_sched_barrier(0);
        const u16* cur = &lds[(g % 3) * BUFE];

        u32x4 bfr[8];
#pragma unroll
        for (int p = 0; p < 8; ++p)
            bfr[p] = *(const u32x4*)(cur + CELEMS + p * 512 + lane * 8);
        u32x4 af[4];
#pragma unroll
        for (int cg = 0; cg < 4; ++cg)
            af[cg] = *(const u32x4*)(cur + (w * 4 + cg) * 512 + lane * 8);

        if (g + 2 < TOTAL) stage(g + 2);   // writes buf (g-1)%3: reads done pre-barrier

        __builtin_amdgcn_s_setprio(1);
#pragma unroll
        for (int cg = 0; cg < 4; ++cg) {
            u32x4 as;
            as.x = (af[cg].x >> 16) | (af[cg].x << 16);
            as.y = (af[cg].y >> 16) | (af[cg].y << 16);
            as.z = (af[cg].z >> 16) | (af[cg].z << 16);
            as.w = (af[cg].w >> 16) | (af[cg].w << 16);
#pragma unroll
            for (int p = 0; p < 8; ++p) {
                acc[cg][p] = __builtin_amdgcn_mfma_f32_16x16x32_bf16(
                    __builtin_bit_cast(bf16x8, af[cg]), __builtin_bit_cast(bf16x8, bfr[p]),
                    acc[cg][p], 0, 0, 0);
                acc[cg][p] = __builtin_amdgcn_mfma_f32_16x16x32_bf16(
                    __builtin_bit_cast(bf16x8, as), __builtin_bit_cast(bf16x8, bfr[p]),
                    acc[cg][p], 0, 0, 0);
            }
        }
        __builtin_amdgcn_s_setprio(0);

        if ((g & (NSTEP - 1)) == NSTEP - 1) {
            // chunk epilogue: dist = cn - 2*dot; running (best, 2nd), codes ascending.
            // cnorm loads here are compiler-tracked (drains pipe 16/512 iters).
            const int chunk = g >> 5;
            const int cb0 = chunk * BC + w * 64;
#pragma unroll
            for (int cg = 0; cg < 4; ++cg) {
                const int code0 = cb0 + cg * 16 + lhi * 4;
                const float4 cn4 = *(const float4*)(cnorm + code0);
                const float cn[4] = {cn4.x, cn4.y, cn4.z, cn4.w};
#pragma unroll
                for (int p = 0; p < 8; ++p) {
                    const f32x4 A = acc[cg][p];
                    const float dv[4] = {cn[0] - 2.f * A.x, cn[1] - 2.f * A.y,
                                         cn[2] - 2.f * A.z, cn[3] - 2.f * A.w};
#pragma unroll
                    for (int r = 0; r < 4; ++r) {
                        if (dv[r] < b1[p]) { b2[p] = b1[p]; b1[p] = dv[r]; i1[p] = code0 + r; }
                        else if (dv[r] < b2[p]) { b2[p] = dv[r]; }
                    }
                    acc[cg][p] = zero;
                }
            }
        }

        if (g + 2 < TOTAL) asm volatile("s_waitcnt vmcnt(5)" ::: "memory");
        else               asm volatile("s_waitcnt vmcnt(0)" ::: "memory");
    }

    // cross-lane merge (lanes {p, p+16, p+32, p+48} hold same point's candidates)
#pragma unroll
    for (int p = 0; p < 8; ++p) {
#pragma unroll
        for (int m = 16; m <= 32; m <<= 1) {
            const float ob1 = __shfl_xor(b1[p], m, 64);
            const float ob2 = __shfl_xor(b2[p], m, 64);
            const int   oi1 = __shfl_xor(i1[p], m, 64);
            const float nb2 = fminf(fminf(b2[p], ob2), fmaxf(b1[p], ob1));
            if (ob1 < b1[p] || (ob1 == b1[p] && oi1 < i1[p])) { b1[p] = ob1; i1[p] = oi1; }
            b2[p] = nb2;
        }
    }

    __syncthreads();   // full drain before LDS reuse

    float* mb1 = (float*)&lds[0];
    float* mb2 = mb1 + 8 * BP;
    int*   mi  = (int*)(mb2 + 8 * BP);
    if (lane < 16) {
#pragma unroll
        for (int p = 0; p < 8; ++p) {
            const int pt = p * 16 + lane;
            mb1[w * BP + pt] = b1[p];
            mb2[w * BP + pt] = b2[p];
            mi [w * BP + pt] = i1[p];
        }
    }
    __syncthreads();
    if (tid < BP) {
        float fb1 = INFINITY, fb2 = INFINITY; int fi = 0;
        for (int ww = 0; ww < 8; ++ww) {
            const float a1 = mb1[ww * BP + tid], a2 = mb2[ww * BP + tid];
            const int   ai = mi[ww * BP + tid];
            const float nb2 = fminf(fminf(fb2, a2), fmaxf(fb1, a1));
            if (a1 < fb1 || (a1 == fb1 && ai < fi)) { fb1 = a1; fi = ai; }
            fb2 = nb2;
        }
        const int n = n0 + tid;
        idx_i[n] = fi;
        idx_f[n] = (float)fi;
        if (fb2 - fb1 < TAU) {
            const int pos = atomicAdd(flag_cnt, 1);
            if ((unsigned)pos < (unsigned)N) flag_list[pos] = n;
        }
    }
}

// ---------------------------------------------------------------------------
// exact f32 re-scan for flagged (small-gap) points
__global__ __launch_bounds__(256) void exact_kernel(
    const float* __restrict__ x, const float* __restrict__ cb,
    const float* __restrict__ cnorm, const int* __restrict__ flag_cnt,
    const int* __restrict__ flag_list, int* __restrict__ idx_i, float* __restrict__ idx_f)
{
    __shared__ float4 xs[D / 4];
    __shared__ float rbv[256];
    __shared__ int   rbi[256];
    const int cnt = min(*flag_cnt, N);
    for (int i = blockIdx.x; i < cnt; i += gridDim.x) {
        const int n = flag_list[i] & (N - 1);
        __syncthreads();
        for (int d = threadIdx.x; d < D / 4; d += 256)
            xs[d] = ((const float4*)(x + (size_t)n * D))[d];
        __syncthreads();
        float best = INFINITY; int besti = 0;
        for (int k = threadIdx.x; k < K; k += 256) {
            const float4* c4 = (const float4*)(cb + (size_t)k * D);
            float a0 = 0.f, a1 = 0.f, a2 = 0.f, a3 = 0.f;
            for (int d = 0; d < D / 4; ++d) {
                const float4 xv = xs[d], cv = c4[d];
                a0 = fmaf(xv.x, cv.x, a0);
                a1 = fmaf(xv.y, cv.y, a1);
                a2 = fmaf(xv.z, cv.z, a2);
                a3 = fmaf(xv.w, cv.w, a3);
            }
            const float dist = cnorm[k] - 2.0f * ((a0 + a1) + (a2 + a3));
            if (dist < best) { best = dist; besti = k; }
        }
        rbv[threadIdx.x] = best; rbi[threadIdx.x] = besti;
        __syncthreads();
        for (int off = 128; off > 0; off >>= 1) {
            if (threadIdx.x < off) {
                const float ov = rbv[threadIdx.x + off];
                const int   oi = rbi[threadIdx.x + off];
                if (ov < rbv[threadIdx.x] ||
                    (ov == rbv[threadIdx.x] && oi < rbi[threadIdx.x])) {
                    rbv[threadIdx.x] = ov; rbi[threadIdx.x] = oi;
                }
            }
            __syncthreads();
        }
        if (threadIdx.x == 0) { idx_i[n] = rbi[0]; idx_f[n] = (float)rbi[0]; }
        __syncthreads();
    }
}

// ---------------------------------------------------------------------------
// zq gather + loss partial (per-block, NO global atomic) + integer counts.
__global__ __launch_bounds__(256) void zq_loss_kernel(
    const float* __restrict__ x, const float* __restrict__ cb,
    const int* __restrict__ idx_i, float* __restrict__ zq,
    int* __restrict__ cnti, double* __restrict__ loss_part)
{
    const int sub = threadIdx.x >> 7;
    const int t   = threadIdx.x & 127;
    const int n   = blockIdx.x * 2 + sub;
    const int k   = idx_i[n] & (K - 1);   // clamp: poison-proof
    const size_t xoff = (size_t)n * 128 + t;
    const size_t coff = (size_t)k * 128 + t;

    const float4 xv = ((const float4*)x)[xoff];
    const float4 qv = ((const float4*)cb)[coff];
    ((float4*)zq)[xoff] = qv;

    const float d0 = xv.x - qv.x, d1 = xv.y - qv.y;
    const float d2 = xv.z - qv.z, d3 = xv.w - qv.w;
    float sq = d0 * d0 + d1 * d1 + d2 * d2 + d3 * d3;

    if (t == 0) atomicAdd(&cnti[k], 1);

#pragma unroll
    for (int m = 32; m >= 1; m >>= 1) sq += __shfl_xor(sq, m, 64);
    __shared__ float partial[4];
    if ((threadIdx.x & 63) == 0) partial[threadIdx.x >> 6] = sq;
    __syncthreads();
    if (threadIdx.x == 0)
        loss_part[blockIdx.x] = (double)(partial[0] + partial[1] + partial[2] + partial[3]);
}

// ---------------------------------------------------------------------------
// single block: prefix-scan counts -> offsets/next, ncs = EMA counts, n_sum.
__global__ __launch_bounds__(256) void scan_kernel(
    const int* __restrict__ cnti, const float* __restrict__ csz,
    int* __restrict__ offs, int* __restrict__ nxt,
    float* __restrict__ ncs, double* __restrict__ n_sum)
{
    __shared__ int    tsum[256];
    __shared__ double dsum[256];
    const int t = threadIdx.x;
    const int base = t * 32;
    int s = 0;
    double dn = 0.0;
#pragma unroll
    for (int i = 0; i < 32; ++i) {
        const int c = cnti[base + i];
        s += c;
        const float v = DECAYF * csz[base + i] + OMDECAY * (float)c;
        ncs[base + i] = v;
        dn += (double)v;
    }
    tsum[t] = s; dsum[t] = dn;
    __syncthreads();
    int run = 0;
    for (int j = 0; j < t; ++j) run += tsum[j];
#pragma unroll
    for (int i = 0; i < 32; ++i) {
        offs[base + i] = run;
        nxt[base + i] = run;
        run += cnti[base + i];
    }
    if (t == 255) offs[K] = run;
    if (t == 0) {
        double tot = 0.0;
        for (int j = 0; j < 256; ++j) tot += dsum[j];
        n_sum[0] = tot;
    }
}

// ---------------------------------------------------------------------------
__global__ __launch_bounds__(256) void fill_kernel(
    const int* __restrict__ idx_i, int* __restrict__ nxt, int* __restrict__ list)
{
    const int p = blockIdx.x * 256 + threadIdx.x;
    const int k = idx_i[p] & (K - 1);
    const int pos = atomicAdd(&nxt[k], 1);
    if ((unsigned)pos < (unsigned)N) list[pos] = p;
}

// ---------------------------------------------------------------------------
// block per code: dw = sum of assigned points (gathered), fused EMA + finalize.
__global__ __launch_bounds__(128) void gather_finalize_kernel(
    const float* __restrict__ x, const int* __restrict__ offs,
    const int* __restrict__ list, const float* __restrict__ ema_w,
    const float* __restrict__ ncs, const double* __restrict__ n_sum,
    float* __restrict__ new_ema, float* __restrict__ new_cb)
{
    const int k = blockIdx.x;
    const int t = threadIdx.x;
    const int beg = min(offs[k], N), end = min(offs[k + 1], N);
    float4 acc = {0.f, 0.f, 0.f, 0.f};
    for (int i = beg; i < end; ++i) {
        const int p = list[i] & (N - 1);
        const float4 v = ((const float4*)x)[(size_t)p * 128 + t];
        acc.x += v.x; acc.y += v.y; acc.z += v.z; acc.w += v.w;
    }
    const float n = (float)n_sum[0];
    const float csm = (ncs[k] + EPSF) / (n + KEPSF) * n;
    const size_t o = (size_t)k * 128 + t;
    const float4 e = ((const float4*)ema_w)[o];
    float4 ne;
    ne.x = DECAYF * e.x + OMDECAY * acc.x;
    ne.y = DECAYF * e.y + OMDECAY * acc.y;
    ne.z = DECAYF * e.z + OMDECAY * acc.z;
    ne.w = DECAYF * e.w + OMDECAY * acc.w;
    ((float4*)new_ema)[o] = ne;
    float4 nc;
    nc.x = ne.x / csm; nc.y = ne.y / csm; nc.z = ne.z / csm; nc.w = ne.w / csm;
    ((float4*)new_cb)[o] = nc;
}

// ---------------------------------------------------------------------------
// deterministic tree-reduce of N/2 per-block loss partials -> loss scalar
__global__ __launch_bounds__(256) void loss_reduce_kernel(
    const double* __restrict__ loss_part, float* __restrict__ out_loss)
{
    __shared__ double red[256];
    const int t = threadIdx.x;
    double s = 0.0;
    for (int i = t; i < N / 2; i += 256) s += loss_part[i];
    red[t] = s;
    __syncthreads();
    for (int off = 128; off > 0; off >>= 1) {
        if (t < off) red[t] += red[t + off];
        __syncthreads();
    }
    if (t == 0)
        out_loss[0] = (float)(1.25 * (red[0] / (double)((size_t)N * D)));
}

// ---------------------------------------------------------------------------
extern "C" void kernel_launch(void* const* d_in, const int* in_sizes, int n_in,
                              void* d_out, int out_size, void* d_ws, size_t ws_size,
                              hipStream_t stream)
{
    const float* z_e   = (const float*)d_in[0];
    const float* cbook = (const float*)d_in[1];
    const float* csz   = (const float*)d_in[2];
    const float* ema_w = (const float*)d_in[3];

    float* out = (float*)d_out;
    u32*   ws  = (u32*)d_ws;

    float*  cnorm     = (float*)(ws + OFF_CNORM);
    int*    idx_i     = (int*)(ws + OFF_IDX);
    int*    cnti      = (int*)(ws + OFF_CNTI);
    int*    nxt       = (int*)(ws + OFF_NEXT);
    int*    offs      = (int*)(ws + OFF_OFFS);
    int*    list      = (int*)(ws + OFF_LIST);
    double* n_sum     = (double*)(ws + OFF_SUMS);
    int*    flag_cnt  = (int*)(ws + OFF_FLAGC);
    int*    flag_list = (int*)(ws + OFF_FLAGL);
    double* loss_part = (double*)(ws + OFF_LOSSP);

    // bf16-split fragment-order scratch in d_out regions overwritten later:
    u16* X2  = (u16*)(out + OUT_ZQ);    // [N/16][32][64][8] — overwritten by zq_loss
    u16* CB2 = (u16*)(out + OUT_NCB);   // [K/16][32][64][8] — overwritten by finalize

    // zero accumulators: cnti .. flag_cnt
    hipMemsetAsync(ws + OFF_CNTI, 0, (OFF_FLAGC + 1 - OFF_CNTI) * sizeof(u32), stream);

    split_frag_kernel<<<N / 16, 256, 0, stream>>>(z_e, (u32x4*)X2);
    split_frag_kernel<<<K / 16, 256, 0, stream>>>(cbook, (u32x4*)CB2);
    row_norm_kernel<<<K / 4, 256, 0, stream>>>(cbook, cnorm);

    argmin_mfma_kernel<<<N / BP, 512, 0, stream>>>(CB2, X2, cnorm, idx_i,
                                                   out + OUT_IDX, flag_cnt, flag_list);

    exact_kernel<<<64, 256, 0, stream>>>(z_e, cbook, cnorm, flag_cnt, flag_list,
                                         idx_i, out + OUT_IDX);

    zq_loss_kernel<<<N / 2, 256, 0, stream>>>(z_e, cbook, idx_i, out + OUT_ZQ,
                                              cnti, loss_part);

    scan_kernel<<<1, 256, 0, stream>>>(cnti, csz, offs, nxt, out + OUT_NCS, n_sum);

    fill_kernel<<<N / 256, 256, 0, stream>>>(idx_i, nxt, list);

    gather_finalize_kernel<<<K, 128, 0, stream>>>(z_e, offs, list, ema_w,
                                                  out + OUT_NCS, n_sum,
                                                  out + OUT_EMA, out + OUT_NCB);

    loss_reduce_kernel<<<1, 256, 0, stream>>>(loss_part, out + OUT_LOSS);
}